// Round 4
// baseline (296.764 us; speedup 1.0000x reference)
//
#include <hip/hip_runtime.h>
#include <hip/hip_bf16.h>
#include <stdint.h>

#define TOKENS 4096
#define IN_F   4096
#define OUT_F  4096
#define NNZ    512

using floatx4 = __attribute__((ext_vector_type(4))) float;
using bf16x8  = __attribute__((ext_vector_type(8))) __bf16;

__device__ __forceinline__ unsigned short f2bf(float f) {
    unsigned int u = __float_as_uint(f);
    u += 0x7FFFu + ((u >> 16) & 1u);   // round-to-nearest-even
    return (unsigned short)(u >> 16);
}

// Prep A: build dense bf16 W. 4 rows per block (1024 blocks x 256 threads):
// zero 32KB LDS, run-leader scatter (rows sorted -> duplicates adjacent,
// leader sums run in fp32, single non-atomic LDS store), then one contiguous
// 32KB coalesced global store.
__global__ __launch_bounds__(256) void prep_w(
        const float* __restrict__ w,
        const int*   __restrict__ mask,
        unsigned short* __restrict__ Wb) {
    __shared__ unsigned short rows[4 * IN_F];   // 32 KB
    const int b = blockIdx.x;
    const int t = threadIdx.x;

    uint4* rv = (uint4*)rows;
#pragma unroll
    for (int e = 0; e < 8; ++e)
        rv[e * 256 + t] = make_uint4(0u, 0u, 0u, 0u);
    __syncthreads();

    const int gbase = b * 4 * NNZ;
#pragma unroll
    for (int e = 0; e < 8; ++e) {
        const int local = e * 256 + t;          // 0..2047
        const int r = local >> 9;               // row within block
        const int k = local & (NNZ - 1);        // pos within row
        const int g = gbase + local;
        const int idx = mask[g];
        if (k == 0 || mask[g - 1] != idx) {     // run leader
            float s = w[g];
            int j = g + 1;
            const int gend = g - k + NNZ;
            while (j < gend && mask[j] == idx) { s += w[j]; ++j; }
            rows[r * IN_F + idx] = f2bf(s);
        }
    }
    __syncthreads();

    uint4* out = (uint4*)(Wb + (size_t)b * 4 * IN_F);
#pragma unroll
    for (int e = 0; e < 8; ++e)
        out[e * 256 + t] = rv[e * 256 + t];
}

// Prep B: convert x fp32 -> bf16, 8 elems/thread.
__global__ __launch_bounds__(256) void prep_x(
        const float* __restrict__ x,
        unsigned short* __restrict__ Xb) {
    const int i = blockIdx.x * 256 + threadIdx.x;
    const float4* xv = (const float4*)x;
    float4 a = xv[2 * i];
    float4 c = xv[2 * i + 1];
    uint4 o;
    o.x = (unsigned)f2bf(a.x) | ((unsigned)f2bf(a.y) << 16);
    o.y = (unsigned)f2bf(a.z) | ((unsigned)f2bf(a.w) << 16);
    o.z = (unsigned)f2bf(c.x) | ((unsigned)f2bf(c.y) << 16);
    o.w = (unsigned)f2bf(c.z) | ((unsigned)f2bf(c.w) << 16);
    ((uint4*)Xb)[i] = o;
}

// GEMM: C[m][n] = sum_k A[m][k] * B[n][k] + bias[n]
// 128x128 tile, 4 waves 2x2, 4x4 of 16x16x32 bf16 MFMA per wave, BK=64,
// global_load_lds width=16 staging. XOR source-seg swizzle (R1) ->
// SQ_LDS_BANK_CONFLICT == 0 (verified R2). Normal (cached) C stores —
// nontemporal measured WORSE (R3: +18MB WRITE_SIZE, +4.7us: defeats L2
// write-combining of the 64B epilogue segments).
//
// R3: L2-locality block swizzle. Row-major order put 32 distinct B-slabs
// (32MB) in each ~64-block temporal window -> per-XCD L2 (4MB) thrash.
// Remap to 4x4 groups of 8x8 patches: window spans 8 A-slabs + 8 B-slabs.
__global__ __launch_bounds__(256) void gemm_bt_bias(
        const unsigned short* __restrict__ A,
        const unsigned short* __restrict__ B,
        const float* __restrict__ bias,
        float* __restrict__ C) {
    __shared__ unsigned short As[128 * 64];
    __shared__ unsigned short Bs[128 * 64];

    const int tid  = threadIdx.x;
    const int wave = tid >> 6;
    const int lane = tid & 63;

    // 8x8 patch swizzle of the 32x32 block grid (bijective)
    const int bid = blockIdx.y * 32 + blockIdx.x;
    const int grp = bid >> 6;                  // 0..15
    const int lcl = bid & 63;                  // 0..63
    const int bx  = (grp & 3) * 8 + (lcl & 7);
    const int by  = (grp >> 2) * 8 + (lcl >> 3);
    const int m0 = by * 128;
    const int n0 = bx * 128;

    const int wm = (wave >> 1) * 64;
    const int wn = (wave & 1) * 64;

    floatx4 acc[4][4] = {};

    const int lrow = lane >> 3;                  // r & 7 for this lane's chunk
    const int kseg = (lane & 7) ^ lrow;          // swizzled source seg
    const int lq   = lane >> 4;
    const int lm   = lane & 15;
    const int lm7  = lm & 7;

    for (int k0 = 0; k0 < IN_F; k0 += 64) {
#pragma unroll
        for (int i = 0; i < 4; ++i) {
            const int cb  = (i * 4 + wave);
            const int row = cb * 8 + lrow;
            const unsigned short* ga =
                A + (size_t)(m0 + row) * IN_F + k0 + kseg * 8;
            const unsigned short* gb =
                B + (size_t)(n0 + row) * IN_F + k0 + kseg * 8;
            __builtin_amdgcn_global_load_lds(
                (__attribute__((address_space(1))) void*)ga,
                (__attribute__((address_space(3))) void*)(As + cb * 512),
                16, 0, 0);
            __builtin_amdgcn_global_load_lds(
                (__attribute__((address_space(1))) void*)gb,
                (__attribute__((address_space(3))) void*)(Bs + cb * 512),
                16, 0, 0);
        }
        __syncthreads();

#pragma unroll
        for (int ks = 0; ks < 2; ++ks) {
            bf16x8 af[4], bfr[4];
#pragma unroll
            for (int mi = 0; mi < 4; ++mi) {
                const int chunk = (ks * 4 + lq) ^ lm7;
                af[mi] = *(const bf16x8*)(As + (wm + mi * 16 + lm) * 64 + chunk * 8);
            }
#pragma unroll
            for (int ni = 0; ni < 4; ++ni) {
                const int chunk = (ks * 4 + lq) ^ lm7;
                bfr[ni] = *(const bf16x8*)(Bs + (wn + ni * 16 + lm) * 64 + chunk * 8);
            }
#pragma unroll
            for (int mi = 0; mi < 4; ++mi)
#pragma unroll
                for (int ni = 0; ni < 4; ++ni)
                    acc[mi][ni] = __builtin_amdgcn_mfma_f32_16x16x32_bf16(
                        af[mi], bfr[ni], acc[mi][ni], 0, 0, 0);
        }
        __syncthreads();
    }

    // Epilogue: C/D layout col = lane&15, row = (lane>>4)*4 + reg  [m89]
#pragma unroll
    for (int ni = 0; ni < 4; ++ni) {
        const int n = n0 + wn + ni * 16 + lm;
        const float bv = bias[n];
#pragma unroll
        for (int mi = 0; mi < 4; ++mi) {
            const int mbase = m0 + wm + mi * 16 + lq * 4;
#pragma unroll
            for (int r = 0; r < 4; ++r) {
                C[(size_t)(mbase + r) * OUT_F + n] = acc[mi][ni][r] + bv;
            }
        }
    }
}

extern "C" void kernel_launch(void* const* d_in, const int* in_sizes, int n_in,
                              void* d_out, int out_size, void* d_ws, size_t ws_size,
                              hipStream_t stream) {
    const float* x    = (const float*)d_in[0];   // [4096,4096] fp32
    const float* w    = (const float*)d_in[1];   // [4096,512]  fp32
    const int*   mask = (const int*)d_in[2];     // [4096,512]  int32 (sorted rows)
    const float* bias = (const float*)d_in[3];   // [4096]      fp32
    float* out = (float*)d_out;                  // [4096,4096] fp32

    unsigned short* Xb = (unsigned short*)d_ws;                 // 32 MiB
    unsigned short* Wb = Xb + (size_t)TOKENS * IN_F;            // 32 MiB

    prep_w<<<OUT_F / 4, 256, 0, stream>>>(w, mask, Wb);
    prep_x<<<8192, 256, 0, stream>>>(x, Xb);
    dim3 grid(32, 32);
    gemm_bt_bias<<<grid, 256, 0, stream>>>(Xb, Wb, bias, out);
}

// Round 5
// 287.775 us; speedup vs baseline: 1.0312x; 1.0312x over previous
//
#include <hip/hip_runtime.h>
#include <hip/hip_bf16.h>
#include <stdint.h>

#define TOKENS 4096
#define IN_F   4096
#define OUT_F  4096
#define NNZ    512

using floatx4 = __attribute__((ext_vector_type(4))) float;
using bf16x8  = __attribute__((ext_vector_type(8))) __bf16;

__device__ __forceinline__ unsigned short f2bf(float f) {
    unsigned int u = __float_as_uint(f);
    u += 0x7FFFu + ((u >> 16) & 1u);   // round-to-nearest-even
    return (unsigned short)(u >> 16);
}

// Single fused prep dispatch (R4 lesson: each extra dispatch in the timed
// region costs ~5-10 us; R2's one-dispatch prep beat R3/R4's two-dispatch).
//  blocks [0, 1024)    : build 4 dense bf16 W rows in LDS (zero + run-leader
//                        scatter on sorted indices, fp32 run sum, non-atomic
//                        store), then one contiguous 32KB coalesced store.
//  blocks [1024, 3072) : convert x fp32 -> bf16, 32 elems/thread.
__global__ __launch_bounds__(256) void prep_fused(
        const float* __restrict__ x,
        const float* __restrict__ w,
        const int*   __restrict__ mask,
        unsigned short* __restrict__ Xb,
        unsigned short* __restrict__ Wb) {
    __shared__ unsigned short rows[4 * IN_F];   // 32 KB (W path only)
    const int b = blockIdx.x;
    const int t = threadIdx.x;

    if (b < 1024) {
        uint4* rv = (uint4*)rows;
#pragma unroll
        for (int e = 0; e < 8; ++e)
            rv[e * 256 + t] = make_uint4(0u, 0u, 0u, 0u);
        __syncthreads();

        const int gbase = b * 4 * NNZ;
#pragma unroll
        for (int e = 0; e < 8; ++e) {
            const int local = e * 256 + t;          // 0..2047
            const int r = local >> 9;               // row within block
            const int k = local & (NNZ - 1);        // pos within row
            const int g = gbase + local;
            const int idx = mask[g];
            if (k == 0 || mask[g - 1] != idx) {     // run leader
                float s = w[g];
                int j = g + 1;
                const int gend = g - k + NNZ;
                while (j < gend && mask[j] == idx) { s += w[j]; ++j; }
                rows[r * IN_F + idx] = f2bf(s);
            }
        }
        __syncthreads();

        uint4* out = (uint4*)(Wb + (size_t)b * 4 * IN_F);
#pragma unroll
        for (int e = 0; e < 8; ++e)
            out[e * 256 + t] = rv[e * 256 + t];
    } else {
        // x-convert: 2048 blocks, each thread 4 uint4 outputs (32 elems)
        const int xb = b - 1024;
        const float4* xv = (const float4*)x;
        uint4* ov = (uint4*)Xb;
#pragma unroll
        for (int e = 0; e < 4; ++e) {
            const int i = xb * 1024 + e * 256 + t;
            float4 a = xv[2 * i];
            float4 c = xv[2 * i + 1];
            uint4 o;
            o.x = (unsigned)f2bf(a.x) | ((unsigned)f2bf(a.y) << 16);
            o.y = (unsigned)f2bf(a.z) | ((unsigned)f2bf(a.w) << 16);
            o.z = (unsigned)f2bf(c.x) | ((unsigned)f2bf(c.y) << 16);
            o.w = (unsigned)f2bf(c.z) | ((unsigned)f2bf(c.w) << 16);
            ov[i] = o;
        }
    }
}

// GEMM: C[m][n] = sum_k A[m][k] * B[n][k] + bias[n]
// 128x128 tile, 4 waves 2x2, 4x4 of 16x16x32 bf16 MFMA per wave, BK=64,
// global_load_lds width=16 staging. XOR source-seg swizzle (R1) ->
// SQ_LDS_BANK_CONFLICT == 0 (verified R2). Normal cached C stores
// (nontemporal measured WORSE, R3: +18MB WRITE_SIZE). Block swizzle kept
// from R3 (neutral, harmless). At the m97-structure plateau (809 TF,
// MfmaUtil 35%, barrier-drain-bound) — frozen.
__global__ __launch_bounds__(256) void gemm_bt_bias(
        const unsigned short* __restrict__ A,
        const unsigned short* __restrict__ B,
        const float* __restrict__ bias,
        float* __restrict__ C) {
    __shared__ unsigned short As[128 * 64];
    __shared__ unsigned short Bs[128 * 64];

    const int tid  = threadIdx.x;
    const int wave = tid >> 6;
    const int lane = tid & 63;

    const int bid = blockIdx.y * 32 + blockIdx.x;
    const int grp = bid >> 6;
    const int lcl = bid & 63;
    const int bx  = (grp & 3) * 8 + (lcl & 7);
    const int by  = (grp >> 2) * 8 + (lcl >> 3);
    const int m0 = by * 128;
    const int n0 = bx * 128;

    const int wm = (wave >> 1) * 64;
    const int wn = (wave & 1) * 64;

    floatx4 acc[4][4] = {};

    const int lrow = lane >> 3;                  // r & 7 for this lane's chunk
    const int kseg = (lane & 7) ^ lrow;          // swizzled source seg
    const int lq   = lane >> 4;
    const int lm   = lane & 15;
    const int lm7  = lm & 7;

    for (int k0 = 0; k0 < IN_F; k0 += 64) {
#pragma unroll
        for (int i = 0; i < 4; ++i) {
            const int cb  = (i * 4 + wave);
            const int row = cb * 8 + lrow;
            const unsigned short* ga =
                A + (size_t)(m0 + row) * IN_F + k0 + kseg * 8;
            const unsigned short* gb =
                B + (size_t)(n0 + row) * IN_F + k0 + kseg * 8;
            __builtin_amdgcn_global_load_lds(
                (__attribute__((address_space(1))) void*)ga,
                (__attribute__((address_space(3))) void*)(As + cb * 512),
                16, 0, 0);
            __builtin_amdgcn_global_load_lds(
                (__attribute__((address_space(1))) void*)gb,
                (__attribute__((address_space(3))) void*)(Bs + cb * 512),
                16, 0, 0);
        }
        __syncthreads();

#pragma unroll
        for (int ks = 0; ks < 2; ++ks) {
            bf16x8 af[4], bfr[4];
#pragma unroll
            for (int mi = 0; mi < 4; ++mi) {
                const int chunk = (ks * 4 + lq) ^ lm7;
                af[mi] = *(const bf16x8*)(As + (wm + mi * 16 + lm) * 64 + chunk * 8);
            }
#pragma unroll
            for (int ni = 0; ni < 4; ++ni) {
                const int chunk = (ks * 4 + lq) ^ lm7;
                bfr[ni] = *(const bf16x8*)(Bs + (wn + ni * 16 + lm) * 64 + chunk * 8);
            }
#pragma unroll
            for (int mi = 0; mi < 4; ++mi)
#pragma unroll
                for (int ni = 0; ni < 4; ++ni)
                    acc[mi][ni] = __builtin_amdgcn_mfma_f32_16x16x32_bf16(
                        af[mi], bfr[ni], acc[mi][ni], 0, 0, 0);
        }
        __syncthreads();
    }

    // Epilogue: C/D layout col = lane&15, row = (lane>>4)*4 + reg  [m89]
#pragma unroll
    for (int ni = 0; ni < 4; ++ni) {
        const int n = n0 + wn + ni * 16 + lm;
        const float bv = bias[n];
#pragma unroll
        for (int mi = 0; mi < 4; ++mi) {
            const int mbase = m0 + wm + mi * 16 + lq * 4;
#pragma unroll
            for (int r = 0; r < 4; ++r) {
                C[(size_t)(mbase + r) * OUT_F + n] = acc[mi][ni][r] + bv;
            }
        }
    }
}

extern "C" void kernel_launch(void* const* d_in, const int* in_sizes, int n_in,
                              void* d_out, int out_size, void* d_ws, size_t ws_size,
                              hipStream_t stream) {
    const float* x    = (const float*)d_in[0];   // [4096,4096] fp32
    const float* w    = (const float*)d_in[1];   // [4096,512]  fp32
    const int*   mask = (const int*)d_in[2];     // [4096,512]  int32 (sorted rows)
    const float* bias = (const float*)d_in[3];   // [4096]      fp32
    float* out = (float*)d_out;                  // [4096,4096] fp32

    unsigned short* Xb = (unsigned short*)d_ws;                 // 32 MiB
    unsigned short* Wb = Xb + (size_t)TOKENS * IN_F;            // 32 MiB

    prep_fused<<<3072, 256, 0, stream>>>(x, w, mask, Xb, Wb);
    dim3 grid(32, 32);
    gemm_bt_bias<<<grid, 256, 0, stream>>>(Xb, Wb, bias, out);
}